// Round 6
// baseline (749.940 us; speedup 1.0000x reference)
//
#include <hip/hip_runtime.h>

// Residual VQ, Q=4 stages, persistent-codebook design.
// Entire bank-striped codebook (64ch x 512 codes = 128 KB) resident in LDS for
// the whole block; 256 blocks (1/CU), each processes 8 point-tiles of 64 pts.
// Per stage: barrier-free 64-channel GEMM into 8x16 register tile, half-wave
// shuffle-butterfly argmin merge, elementwise residual update in LDS.
// Numerics identical to R5 (passing): score = -csq/2 + dot, strict-> argmax,
// ascending-k tie-break, exact elementwise residual/loss, sequential-order
// code-sum epilogue.
//
// d_out: quantized [8,64,128,128] (8388608 f32) | indices as float
//        [8,128,128,4] (524288) | commit_loss [4].
// d_ws: cbS [64][512] bank-striped transposed codebook + csq [512].

#define NPTS   131072
#define CH     64
#define KCODE  512
#define NQ     4
#define HW     16384
#define BPTS   64        // points per tile
#define BTHR   256       // threads per block (4 waves)
#define NTILE  (NPTS / BPTS)   // 2048
#define GRID   256

__device__ __forceinline__ void load_lds16(const float* g, float* l) {
    __builtin_amdgcn_global_load_lds(
        (const __attribute__((address_space(1))) void*)g,
        (__attribute__((address_space(3))) void*)l, 16, 0, 0);
}

// cbS[c*512 + pos] = cb[k*64 + c], pos(k) = i*128 + cg*4 + j for k = cg*16+i*4+j
__global__ void prep_cbS(const float* __restrict__ cb, float* __restrict__ cbS) {
    int g = blockIdx.x * 256 + threadIdx.x;   // 0..32767
    int c = g >> 9, pos = g & 511;
    int i = pos >> 7, cg = (pos >> 2) & 31, j = pos & 3;
    int k = cg * 16 + i * 4 + j;
    cbS[g] = cb[k * CH + c];
}

__global__ void prep_csq(const float* __restrict__ cb, float* __restrict__ csq) {
    int k = blockIdx.x * 256 + threadIdx.x;
    if (k < KCODE) {
        const float4* row = (const float4*)(cb + (size_t)k * CH);
        float a0 = 0.f, a1 = 0.f, a2 = 0.f, a3 = 0.f;
#pragma unroll
        for (int j = 0; j < CH / 4; ++j) {
            float4 v = row[j];
            a0 = fmaf(v.x, v.x, a0); a1 = fmaf(v.y, v.y, a1);
            a2 = fmaf(v.z, v.z, a2); a3 = fmaf(v.w, v.w, a3);
        }
        csq[k] = (a0 + a1) + (a2 + a3);
    }
}

__global__ __launch_bounds__(BTHR, 1) void rvq_main(
    const float* __restrict__ x, const float* __restrict__ cb,
    const float* __restrict__ cbS, const float* __restrict__ csq_g,
    float* __restrict__ out_quant, float* __restrict__ out_idx,
    float* __restrict__ out_loss)
{
    __shared__ __align__(16) float s_cb[CH * KCODE];   // 128 KB persistent codebook
    __shared__ __align__(16) float s_res[CH * BPTS];   // 16 KB residual [c][p]
    __shared__ __align__(16) float s_csq[KCODE];       // 2 KB
    __shared__ int   s_bidx[BPTS];                     // 256 B
    __shared__ int   s_idx4[BPTS * NQ];                // 1 KB
    __shared__ float s_ls[4 * BPTS];                   // 1 KB loss partials

    const int tid  = threadIdx.x;
    const int lane = tid & 63;
    const int w    = tid >> 6;
    const int cg   = tid & 31;   // 16 codes: k = cg*16 + n
    const int pg   = tid >> 5;   // 8 points: p = pg*8 .. pg*8+7

    // ---- stage full codebook + csq into LDS (once per block) ----
#pragma unroll
    for (int i = 0; i < 32; ++i)
        load_lds16(cbS + i * 1024 + w * 256 + lane * 4,
                   s_cb + i * 1024 + w * 256);
    for (int j = tid; j < KCODE; j += BTHR) s_csq[j] = csq_g[j];

    float lacc[NQ] = {0.f, 0.f, 0.f, 0.f};

    for (int tile = blockIdx.x; tile < NTILE; tile += GRID) {
        const int n0  = tile * BPTS;         // tile never straddles batch index
        const int b   = n0 >> 14;
        const int hw0 = n0 & (HW - 1);
        const float* xbase = x + (size_t)b * CH * HW + hw0;

        __syncthreads();   // prev tile's epilogue reads of s_res done
                           // (first iter: trivially fine)
        for (int j = tid; j < CH * BPTS / 4; j += BTHR) {
            int c = j >> 4, p4 = j & 15;
            *(float4*)&s_res[c * BPTS + p4 * 4] =
                *(const float4*)(xbase + (size_t)c * HW + p4 * 4);
        }
        __syncthreads();   // s_res visible; first iter: also drains s_cb vmcnt

        float lossq[NQ], idxf[NQ];

        for (int q = 0; q < NQ; ++q) {
            // ---- acc init = -csq/2 ----
            float acc[8][16];
            {
                const float4* cq4 = (const float4*)(s_csq + cg * 16);
                float4 c0 = cq4[0], c1 = cq4[1], c2 = cq4[2], c3 = cq4[3];
                float ci[16] = {c0.x, c0.y, c0.z, c0.w, c1.x, c1.y, c1.z, c1.w,
                                c2.x, c2.y, c2.z, c2.w, c3.x, c3.y, c3.z, c3.w};
#pragma unroll
                for (int p = 0; p < 8; ++p)
#pragma unroll
                    for (int n = 0; n < 16; ++n) acc[p][n] = -0.5f * ci[n];
            }

            // ---- barrier-free GEMM over all 64 channels ----
#pragma unroll 4
            for (int c = 0; c < CH; ++c) {
                const float* ar = &s_res[c * BPTS + pg * 8];
                float4 a0 = *(const float4*)(ar + 0);
                float4 a1 = *(const float4*)(ar + 4);
                float av[8] = {a0.x, a0.y, a0.z, a0.w, a1.x, a1.y, a1.z, a1.w};
                const float* br = &s_cb[c * KCODE + cg * 4];
#pragma unroll
                for (int nb = 0; nb < 4; ++nb) {
                    float4 bq = *(const float4*)(br + nb * 128);
#pragma unroll
                    for (int p = 0; p < 8; ++p) {
                        acc[p][nb * 4 + 0] = fmaf(av[p], bq.x, acc[p][nb * 4 + 0]);
                        acc[p][nb * 4 + 1] = fmaf(av[p], bq.y, acc[p][nb * 4 + 1]);
                        acc[p][nb * 4 + 2] = fmaf(av[p], bq.z, acc[p][nb * 4 + 2]);
                        acc[p][nb * 4 + 3] = fmaf(av[p], bq.w, acc[p][nb * 4 + 3]);
                    }
                }
            }

            // ---- per-thread argmax over own 16 codes (ascending k, strict >) ----
            float bd[8]; int bi[8];
#pragma unroll
            for (int p = 0; p < 8; ++p) {
                float B = acc[p][0]; int I = cg * 16;
#pragma unroll
                for (int n = 1; n < 16; ++n)
                    if (acc[p][n] > B) { B = acc[p][n]; I = cg * 16 + n; }
                bd[p] = B; bi[p] = I;
            }

            // ---- half-wave butterfly merge across the 32 cg-lanes ----
            // (lanes 0-31 of a wave are pg=2w, lanes 32-63 are pg=2w+1; xor
            //  masks 1..16 stay within the half-wave)
#pragma unroll
            for (int m = 1; m <= 16; m <<= 1) {
#pragma unroll
                for (int p = 0; p < 8; ++p) {
                    float oB = __shfl_xor(bd[p], m, 64);
                    int   oI = __shfl_xor(bi[p], m, 64);
                    if (oB > bd[p] || (oB == bd[p] && oI < bi[p])) {
                        bd[p] = oB; bi[p] = oI;
                    }
                }
            }
            if (cg == 0) {
#pragma unroll
                for (int p = 0; p < 8; ++p) {
                    s_bidx[pg * 8 + p] = bi[p];
                    s_idx4[(pg * 8 + p) * 4 + q] = bi[p];
                }
            }
            __syncthreads();   // (c) s_bidx visible
            if (tid < BPTS) idxf[q] = (float)s_bidx[tid];

            // ---- residual update (exact r' = r - c) + loss partials ----
            {
                const int p  = tid & 63;
                const int cq = tid >> 6;   // 16-channel quarter
                int bix = s_bidx[p];
                const float4* crow =
                    (const float4*)(cb + (size_t)bix * CH + cq * 16);
                float l0 = 0.f, l1 = 0.f, l2 = 0.f, l3 = 0.f;
#pragma unroll
                for (int i = 0; i < 4; ++i) {
                    float4 v = crow[i];
                    int c = cq * 16 + i * 4;
                    float r0 = s_res[(c + 0) * BPTS + p] - v.x;
                    float r1 = s_res[(c + 1) * BPTS + p] - v.y;
                    float r2 = s_res[(c + 2) * BPTS + p] - v.z;
                    float r3 = s_res[(c + 3) * BPTS + p] - v.w;
                    s_res[(c + 0) * BPTS + p] = r0;
                    s_res[(c + 1) * BPTS + p] = r1;
                    s_res[(c + 2) * BPTS + p] = r2;
                    s_res[(c + 3) * BPTS + p] = r3;
                    l0 = fmaf(r0, r0, l0); l1 = fmaf(r1, r1, l1);
                    l2 = fmaf(r2, r2, l2); l3 = fmaf(r3, r3, l3);
                }
                s_ls[cq * BPTS + p] = (l0 + l1) + (l2 + l3);
            }
            __syncthreads();   // (d) s_res + s_ls visible
            if (tid < BPTS)
                lossq[q] = (s_ls[0 * BPTS + tid] + s_ls[1 * BPTS + tid]) +
                           (s_ls[2 * BPTS + tid] + s_ls[3 * BPTS + tid]);
        }

        // ---- epilogue: quantized = sum of 4 chosen code rows (seq order) ----
        {
            const int p  = tid & 63;
            const int cq = tid >> 6;
            int e0 = s_idx4[p * 4 + 0], e1 = s_idx4[p * 4 + 1];
            int e2 = s_idx4[p * 4 + 2], e3 = s_idx4[p * 4 + 3];
            const float4* r0 = (const float4*)(cb + (size_t)e0 * CH + cq * 16);
            const float4* r1 = (const float4*)(cb + (size_t)e1 * CH + cq * 16);
            const float4* r2 = (const float4*)(cb + (size_t)e2 * CH + cq * 16);
            const float4* r3 = (const float4*)(cb + (size_t)e3 * CH + cq * 16);
            float* ob = out_quant + (size_t)b * CH * HW + hw0;
#pragma unroll
            for (int i = 0; i < 4; ++i) {
                float4 v0 = r0[i], v1 = r1[i], v2 = r2[i], v3 = r3[i];
                float s0 = ((v0.x + v1.x) + v2.x) + v3.x;
                float s1 = ((v0.y + v1.y) + v2.y) + v3.y;
                float s2 = ((v0.z + v1.z) + v2.z) + v3.z;
                float s3 = ((v0.w + v1.w) + v2.w) + v3.w;
                int c = cq * 16 + i * 4;
                ob[(size_t)(c + 0) * HW + p] = s0;
                ob[(size_t)(c + 1) * HW + p] = s1;
                ob[(size_t)(c + 2) * HW + p] = s2;
                ob[(size_t)(c + 3) * HW + p] = s3;
            }
        }

        if (tid < BPTS) {
            ((float4*)out_idx)[n0 + tid] =
                make_float4(idxf[0], idxf[1], idxf[2], idxf[3]);
#pragma unroll
            for (int qq = 0; qq < NQ; ++qq) lacc[qq] += lossq[qq];
        }
    }

    // ---- commit loss: reduce accumulated partials (owners = wave 0) ----
    if (tid < BPTS) {
#pragma unroll
        for (int qq = 0; qq < NQ; ++qq) {
            float v = lacc[qq];
            for (int off = 32; off > 0; off >>= 1) v += __shfl_down(v, off, 64);
            if (tid == 0)
                atomicAdd(&out_loss[qq], v * (1.0f / 8388608.0f));  // /(NPTS*CH)
        }
    }
}

extern "C" void kernel_launch(void* const* d_in, const int* in_sizes, int n_in,
                              void* d_out, int out_size, void* d_ws, size_t ws_size,
                              hipStream_t stream) {
    const float* x  = (const float*)d_in[0];
    const float* cb = (const float*)d_in[1];
    float* out       = (float*)d_out;
    float* out_quant = out;                    // 8388608
    float* out_idx   = out + 8388608;          // 524288
    float* out_loss  = out + 8388608 + 524288; // 4

    float* cbS = (float*)d_ws;                 // 64*512 floats
    float* csq = cbS + CH * KCODE;             // 512 floats

    hipMemsetAsync(out_loss, 0, NQ * sizeof(float), stream);
    prep_cbS<<<(CH * KCODE) / 256, 256, 0, stream>>>(cb, cbS);
    prep_csq<<<2, 256, 0, stream>>>(cb, csq);
    rvq_main<<<GRID, BTHR, 0, stream>>>(x, cb, cbS, csq,
                                        out_quant, out_idx, out_loss);
}

// Round 7
// 521.137 us; speedup vs baseline: 1.4390x; 1.4390x over previous
//
#include <hip/hip_runtime.h>

// Residual VQ, Q=4 stages. R7 = R5 numerics (passing, bit-exact path) with a
// restructured K-loop: 8-channel double-buffered codebook chunks staged via
// global_load_lds, prefetch issued a full chunk ahead of the draining barrier;
// butterfly in-register argmin merge (R6-proven). 52.25 KB LDS -> 3 blocks/CU.
//
// d_out: quantized [8,64,128,128] (8388608 f32) | indices as float
//        [8,128,128,4] (524288) | commit_loss [4].
// d_ws: cbS [64][512] bank-striped transposed codebook + csq [512].

#define NPTS   131072
#define CH     64
#define KCODE  512
#define NQ     4
#define HW     16384
#define BPTS   64        // points per block
#define BTHR   256       // threads per block (4 waves)
#define CCH    8         // channels per chunk
#define NCHK   8         // chunks per stage (CH / CCH)

__device__ __forceinline__ void load_lds16(const float* g, float* l) {
    __builtin_amdgcn_global_load_lds(
        (const __attribute__((address_space(1))) void*)g,
        (__attribute__((address_space(3))) void*)l, 16, 0, 0);
}

// cbS[c*512 + pos] = cb[k*64 + c], pos(k) = i*128 + cg*4 + j for k = cg*16+i*4+j
__global__ void prep_cbS(const float* __restrict__ cb, float* __restrict__ cbS) {
    int g = blockIdx.x * 256 + threadIdx.x;   // 0..32767
    int c = g >> 9, pos = g & 511;
    int i = pos >> 7, cg = (pos >> 2) & 31, j = pos & 3;
    int k = cg * 16 + i * 4 + j;
    cbS[g] = cb[k * CH + c];
}

__global__ void prep_csq(const float* __restrict__ cb, float* __restrict__ csq) {
    int k = blockIdx.x * 256 + threadIdx.x;
    if (k < KCODE) {
        const float4* row = (const float4*)(cb + (size_t)k * CH);
        float a0 = 0.f, a1 = 0.f, a2 = 0.f, a3 = 0.f;
#pragma unroll
        for (int j = 0; j < CH / 4; ++j) {
            float4 v = row[j];
            a0 = fmaf(v.x, v.x, a0); a1 = fmaf(v.y, v.y, a1);
            a2 = fmaf(v.z, v.z, a2); a3 = fmaf(v.w, v.w, a3);
        }
        csq[k] = (a0 + a1) + (a2 + a3);
    }
}

__global__ __launch_bounds__(BTHR, 3) void rvq_main(
    const float* __restrict__ x, const float* __restrict__ cb,
    const float* __restrict__ cbS, const float* __restrict__ csq_g,
    float* __restrict__ out_quant, float* __restrict__ out_idx,
    float* __restrict__ out_loss)
{
    __shared__ __align__(16) float s_res[CH * BPTS];        // 16 KB residual [c][p]
    __shared__ __align__(16) float s_buf[2][CCH * KCODE];   // 2 x 16 KB chunk buffers
    __shared__ __align__(16) float s_csq[KCODE];            // 2 KB
    __shared__ int   s_bidx[BPTS];                          // 256 B
    __shared__ int   s_idx4[BPTS * NQ];                     // 1 KB
    __shared__ float s_ls[4 * BPTS];                        // 1 KB

    const int tid  = threadIdx.x;
    const int lane = tid & 63;
    const int w    = tid >> 6;
    const int cg   = tid & 31;   // 16 codes: k = cg*16 + n
    const int pg   = tid >> 5;   // 8 points: p = pg*8 .. pg*8+7

    const int n0  = blockIdx.x * BPTS;   // block never straddles batch index
    const int b   = n0 >> 14;
    const int hw0 = n0 & (HW - 1);
    const float* xbase = x + (size_t)b * CH * HW + hw0;

    // ---- prefetch stage-0 chunk 0 into buf[0] (overlaps x-tile load) ----
#pragma unroll
    for (int r = 0; r < 4; ++r) {
        int off = (w * 4 + r) * 256;
        load_lds16(cbS + off + lane * 4, &s_buf[0][off]);
    }

    // ---- x tile -> s_res, csq -> s_csq ----
    for (int j = tid; j < CH * BPTS / 4; j += BTHR) {
        int c = j >> 4, p4 = j & 15;
        *(float4*)&s_res[c * BPTS + p4 * 4] =
            *(const float4*)(xbase + (size_t)c * HW + p4 * 4);
    }
    for (int j = tid; j < KCODE; j += BTHR) s_csq[j] = csq_g[j];
    __syncthreads();   // s_res/s_csq visible, buf[0] drained

    float lossq[NQ], idxf[NQ];

    for (int q = 0; q < NQ; ++q) {
        // ---- acc init = -csq/2 (score form; equiv to csq-2*dot compare) ----
        float acc[8][16];
        {
            const float4* cq4 = (const float4*)(s_csq + cg * 16);
            float4 c0 = cq4[0], c1 = cq4[1], c2 = cq4[2], c3 = cq4[3];
            float ci[16] = {c0.x, c0.y, c0.z, c0.w, c1.x, c1.y, c1.z, c1.w,
                            c2.x, c2.y, c2.z, c2.w, c3.x, c3.y, c3.z, c3.w};
#pragma unroll
            for (int p = 0; p < 8; ++p)
#pragma unroll
                for (int n = 0; n < 16; ++n) acc[p][n] = -0.5f * ci[n];
        }

        // ---- GEMM: 8 chunks x 8 channels, double-buffered ----
        for (int chk = 0; chk < NCHK; ++chk) {
            // prefetch next chunk (chunk 0 of next stage on wrap) into the
            // other buffer; it has the whole current chunk's compute to land.
            if (!(q == NQ - 1 && chk == NCHK - 1)) {
                const int nchk = (chk + 1 < NCHK) ? chk + 1 : 0;
                const float* src = cbS + nchk * (CCH * KCODE);
                float* dst = s_buf[(chk + 1) & 1];
#pragma unroll
                for (int r = 0; r < 4; ++r) {
                    int off = (w * 4 + r) * 256;
                    load_lds16(src + off + lane * 4, dst + off);
                }
            }

            const float* bufp = s_buf[chk & 1];
#pragma unroll 2
            for (int c = 0; c < CCH; ++c) {
                const float* ar = &s_res[(chk * CCH + c) * BPTS + pg * 8];
                float4 a0 = *(const float4*)(ar + 0);
                float4 a1 = *(const float4*)(ar + 4);
                float av[8] = {a0.x, a0.y, a0.z, a0.w, a1.x, a1.y, a1.z, a1.w};
                const float* br = &bufp[c * KCODE + cg * 4];
#pragma unroll
                for (int nb = 0; nb < 4; ++nb) {
                    float4 bq = *(const float4*)(br + nb * 128);
#pragma unroll
                    for (int p = 0; p < 8; ++p) {
                        acc[p][nb * 4 + 0] = fmaf(av[p], bq.x, acc[p][nb * 4 + 0]);
                        acc[p][nb * 4 + 1] = fmaf(av[p], bq.y, acc[p][nb * 4 + 1]);
                        acc[p][nb * 4 + 2] = fmaf(av[p], bq.z, acc[p][nb * 4 + 2]);
                        acc[p][nb * 4 + 3] = fmaf(av[p], bq.w, acc[p][nb * 4 + 3]);
                    }
                }
            }
            __syncthreads();   // all waves done with buf[chk&1]; prefetch drained
        }

        // ---- per-thread argmax over own 16 codes (ascending k, strict >) ----
        float bd[8]; int bi[8];
#pragma unroll
        for (int p = 0; p < 8; ++p) {
            float B = acc[p][0]; int I = cg * 16;
#pragma unroll
            for (int n = 1; n < 16; ++n)
                if (acc[p][n] > B) { B = acc[p][n]; I = cg * 16 + n; }
            bd[p] = B; bi[p] = I;
        }

        // ---- half-wave butterfly merge across the 32 cg-lanes (in-register) ----
#pragma unroll
        for (int m = 1; m <= 16; m <<= 1) {
#pragma unroll
            for (int p = 0; p < 8; ++p) {
                float oB = __shfl_xor(bd[p], m, 64);
                int   oI = __shfl_xor(bi[p], m, 64);
                if (oB > bd[p] || (oB == bd[p] && oI < bi[p])) {
                    bd[p] = oB; bi[p] = oI;
                }
            }
        }
        if (cg == 0) {
#pragma unroll
            for (int p = 0; p < 8; ++p) {
                s_bidx[pg * 8 + p] = bi[p];
                s_idx4[(pg * 8 + p) * 4 + q] = bi[p];
            }
        }
        __syncthreads();   // s_bidx visible
        if (tid < BPTS) idxf[q] = (float)s_bidx[tid];

        // ---- residual update (exact r' = r - c) + loss partials ----
        {
            const int p  = tid & 63;
            const int cq = tid >> 6;   // 16-channel quarter
            int bix = s_bidx[p];
            const float4* crow = (const float4*)(cb + (size_t)bix * CH + cq * 16);
            float l0 = 0.f, l1 = 0.f, l2 = 0.f, l3 = 0.f;
#pragma unroll
            for (int i = 0; i < 4; ++i) {
                float4 v = crow[i];
                int c = cq * 16 + i * 4;
                float r0 = s_res[(c + 0) * BPTS + p] - v.x;
                float r1 = s_res[(c + 1) * BPTS + p] - v.y;
                float r2 = s_res[(c + 2) * BPTS + p] - v.z;
                float r3 = s_res[(c + 3) * BPTS + p] - v.w;
                s_res[(c + 0) * BPTS + p] = r0;
                s_res[(c + 1) * BPTS + p] = r1;
                s_res[(c + 2) * BPTS + p] = r2;
                s_res[(c + 3) * BPTS + p] = r3;
                l0 = fmaf(r0, r0, l0); l1 = fmaf(r1, r1, l1);
                l2 = fmaf(r2, r2, l2); l3 = fmaf(r3, r3, l3);
            }
            s_ls[cq * BPTS + p] = (l0 + l1) + (l2 + l3);
        }
        __syncthreads();   // s_res + s_ls visible
        if (tid < BPTS)
            lossq[q] = (s_ls[0 * BPTS + tid] + s_ls[1 * BPTS + tid]) +
                       (s_ls[2 * BPTS + tid] + s_ls[3 * BPTS + tid]);
    }

    // ---- epilogue: quantized = sum of 4 chosen code rows (sequential order) ----
    {
        const int p  = tid & 63;
        const int cq = tid >> 6;
        int e0 = s_idx4[p * 4 + 0], e1 = s_idx4[p * 4 + 1];
        int e2 = s_idx4[p * 4 + 2], e3 = s_idx4[p * 4 + 3];
        const float4* r0 = (const float4*)(cb + (size_t)e0 * CH + cq * 16);
        const float4* r1 = (const float4*)(cb + (size_t)e1 * CH + cq * 16);
        const float4* r2 = (const float4*)(cb + (size_t)e2 * CH + cq * 16);
        const float4* r3 = (const float4*)(cb + (size_t)e3 * CH + cq * 16);
        float* ob = out_quant + (size_t)b * CH * HW + hw0;
#pragma unroll
        for (int i = 0; i < 4; ++i) {
            float4 v0 = r0[i], v1 = r1[i], v2 = r2[i], v3 = r3[i];
            float s0 = ((v0.x + v1.x) + v2.x) + v3.x;
            float s1 = ((v0.y + v1.y) + v2.y) + v3.y;
            float s2 = ((v0.z + v1.z) + v2.z) + v3.z;
            float s3 = ((v0.w + v1.w) + v2.w) + v3.w;
            int c = cq * 16 + i * 4;
            ob[(size_t)(c + 0) * HW + p] = s0;
            ob[(size_t)(c + 1) * HW + p] = s1;
            ob[(size_t)(c + 2) * HW + p] = s2;
            ob[(size_t)(c + 3) * HW + p] = s3;
        }
    }

    // ---- indices + commit loss (owners are exactly wave 0) ----
    if (tid < BPTS) {
        ((float4*)out_idx)[n0 + tid] =
            make_float4(idxf[0], idxf[1], idxf[2], idxf[3]);
#pragma unroll
        for (int qq = 0; qq < NQ; ++qq) {
            float v = lossq[qq];
            for (int off = 32; off > 0; off >>= 1) v += __shfl_down(v, off, 64);
            if (tid == 0)
                atomicAdd(&out_loss[qq], v * (1.0f / 8388608.0f));  // /(NPTS*CH)
        }
    }
}

extern "C" void kernel_launch(void* const* d_in, const int* in_sizes, int n_in,
                              void* d_out, int out_size, void* d_ws, size_t ws_size,
                              hipStream_t stream) {
    const float* x  = (const float*)d_in[0];
    const float* cb = (const float*)d_in[1];
    float* out       = (float*)d_out;
    float* out_quant = out;                    // 8388608
    float* out_idx   = out + 8388608;          // 524288
    float* out_loss  = out + 8388608 + 524288; // 4

    float* cbS = (float*)d_ws;                 // 64*512 floats
    float* csq = cbS + CH * KCODE;             // 512 floats

    hipMemsetAsync(out_loss, 0, NQ * sizeof(float), stream);
    prep_cbS<<<(CH * KCODE) / 256, 256, 0, stream>>>(cb, cbS);
    prep_csq<<<2, 256, 0, stream>>>(cb, csq);
    rvq_main<<<NPTS / BPTS, BTHR, 0, stream>>>(x, cb, cbS, csq,
                                               out_quant, out_idx, out_loss);
}